// Round 1
// 3622.786 us; speedup vs baseline: 2.3845x; 2.3845x over previous
//
#include <hip/hip_runtime.h>

#define B_   64
#define F_   2048
#define P_   196
#define T_   25
#define E_   512
#define H_   512
#define A_   512
#define V_   30000

typedef __attribute__((ext_vector_type(8))) short short8;
typedef __attribute__((ext_vector_type(4))) float floatx4;

__device__ __forceinline__ float bu2f(unsigned short u) {
    union { unsigned int i; float f; } c; c.i = ((unsigned int)u) << 16; return c.f;
}
__device__ __forceinline__ unsigned short f2bu(float x) {
    unsigned int u = __float_as_uint(x);
    return (unsigned short)((u + 0x7FFFu + ((u >> 16) & 1u)) >> 16);  // RNE
}
__device__ __forceinline__ float wave_reduce(float v) {
    #pragma unroll
    for (int off = 32; off; off >>= 1) v += __shfl_down(v, off);
    return v;
}

// ---------------- one-time prep ----------------

// mean over P: meanf[b*F+f]
__global__ void k_mean(const float* __restrict__ cnn, float* __restrict__ meanf) {
    int wave = (blockIdx.x * blockDim.x + threadIdx.x) >> 6;
    int lane = threadIdx.x & 63;
    if (wave >= B_ * F_) return;
    const float* row = cnn + (size_t)wave * P_;
    float acc = 0.f;
    for (int p = lane; p < P_; p += 64) acc += row[p];
    acc = wave_reduce(acc);
    if (lane == 0) meanf[wave] = acc * (1.0f / P_);
}

// h0 = meanf @ W_init + b_init (fp32 exact, one-time) + bf16 copy
__global__ void k_h0(const float* __restrict__ meanf, const float* __restrict__ Wi,
                     const float* __restrict__ bi, float* __restrict__ h0,
                     unsigned short* __restrict__ h0b) {
    int idx = blockIdx.x * blockDim.x + threadIdx.x;
    if (idx >= B_ * H_) return;
    int b = idx >> 9, h = idx & 511;
    const float* m = meanf + (size_t)b * F_;
    const float* w = Wi + h;
    float a0 = 0.f, a1 = 0.f, a2 = 0.f, a3 = 0.f;
    for (int f = 0; f < F_; f += 4) {
        a0 += m[f + 0] * w[(size_t)(f + 0) * H_];
        a1 += m[f + 1] * w[(size_t)(f + 1) * H_];
        a2 += m[f + 2] * w[(size_t)(f + 2) * H_];
        a3 += m[f + 3] * w[(size_t)(f + 3) * H_];
    }
    float v = a0 + a1 + a2 + a3 + bi[h];
    h0[idx] = v;
    h0b[idx] = f2bu(v);
}

// straight fp32 -> bf16 convert, 4 elems/thread
__global__ void k_cvt(const float* __restrict__ in, unsigned short* __restrict__ out, int n4) {
    int i = blockIdx.x * blockDim.x + threadIdx.x;
    if (i >= n4) return;
    float4 v = ((const float4*)in)[i];
    ushort4 o;
    o.x = f2bu(v.x); o.y = f2bu(v.y); o.z = f2bu(v.z); o.w = f2bu(v.w);
    ((ushort4*)out)[i] = o;
}

// transpose-convert: in fp32 [R][C] -> out bf16 [C][R]
__global__ void k_tc(const float* __restrict__ in, unsigned short* __restrict__ out,
                     int R, int C) {
    __shared__ float tile[64][65];
    int tid = threadIdx.x;
    int c0 = blockIdx.x * 64, r0 = blockIdx.y * 64;
    #pragma unroll
    for (int i = 0; i < 16; ++i) {
        int r = (tid >> 6) + i * 4, c = tid & 63;
        tile[r][c] = (r0 + r < R && c0 + c < C) ? in[(size_t)(r0 + r) * C + c0 + c] : 0.f;
    }
    __syncthreads();
    #pragma unroll
    for (int i = 0; i < 16; ++i) {
        int c = (tid >> 6) + i * 4, r = tid & 63;
        if (c0 + c < C && r0 + r < R)
            out[(size_t)(c0 + c) * R + r0 + r] = f2bu(tile[r][c]);
    }
}

// gather caption embeddings -> bf16 [T*B][E], row = t*64+b
__global__ void k_capemb(const float* __restrict__ emb, const int* __restrict__ icap,
                         unsigned short* __restrict__ ce) {
    int row = blockIdx.x;
    int t = row >> 6, b = row & 63;
    int tok = icap[b * T_ + t];
    const float* src = emb + (size_t)tok * E_;
    unsigned short* dst = ce + (size_t)row * E_;
    int e = threadIdx.x;
    dst[e] = f2bu(src[e]);
    dst[e + 256] = f2bu(src[e + 256]);
}

// ---------------- MFMA GEMMs ----------------
// LDS tile layout: [rows][64 k] bf16, 8-bf16 chunk XOR-swizzled by (row&7)
__device__ __forceinline__ short8 frag_ld(const unsigned short* T, int row, int chunk) {
    return *(const short8*)(T + row * 64 + (((chunk) ^ (row & 7)) << 3));
}

// C[M x N] = A[M x K] * BT[N x K]^T (+bias)
// AMODE 0: A bf16 row-major stride sA; AMODE 1: A[row][k] = cnn[(b*F+k)*P+p], row=b*196+p
template<int AMODE, int OUTBF16>
__global__ __launch_bounds__(256) void k_gemm_big(
        const void* __restrict__ Ap, int sA,
        const unsigned short* __restrict__ BT, int sB,
        const float* __restrict__ bias,
        void* __restrict__ Cp, int ldC, int M, int N, int K) {
    __shared__ unsigned short As[128 * 64];
    __shared__ unsigned short Bs[128 * 64];
    int tid = threadIdx.x;
    int row0 = blockIdx.x * 128, col0 = blockIdx.y * 128;
    int w = tid >> 6, lane = tid & 63;
    int wm = (w >> 1) * 64, wn = (w & 1) * 64;
    floatx4 acc[4][4] = {};
    for (int k0 = 0; k0 < K; k0 += 64) {
        if (AMODE == 0) {
            const unsigned short* A = (const unsigned short*)Ap;
            #pragma unroll
            for (int i = 0; i < 4; ++i) {
                int e = (tid + i * 256) * 8;
                int r = e >> 6, k = e & 63;
                uint4 v = make_uint4(0, 0, 0, 0);
                int gr = row0 + r;
                if (gr < M) v = *(const uint4*)(A + (size_t)gr * sA + k0 + k);
                *(uint4*)(As + r * 64 + (((k >> 3) ^ (r & 7)) << 3)) = v;
            }
        } else {
            const float* cnn = (const float*)Ap;
            #pragma unroll
            for (int i = 0; i < 32; ++i) {
                int e = tid + i * 256;
                int r = e & 127, kk = e >> 7;
                unsigned int grow = (unsigned int)(row0 + r);
                unsigned int b = (grow * 171197u) >> 25;   // exact /196 for grow<186413
                unsigned int p = grow - b * 196u;
                float v = cnn[((size_t)b * F_ + (k0 + kk)) * P_ + p];
                As[r * 64 + (((kk >> 3) ^ (r & 7)) << 3) + (kk & 7)] = f2bu(v);
            }
        }
        #pragma unroll
        for (int i = 0; i < 4; ++i) {
            int e = (tid + i * 256) * 8;
            int r = e >> 6, k = e & 63;
            uint4 v = make_uint4(0, 0, 0, 0);
            int gc = col0 + r;
            if (gc < N) v = *(const uint4*)(BT + (size_t)gc * sB + k0 + k);
            *(uint4*)(Bs + r * 64 + (((k >> 3) ^ (r & 7)) << 3)) = v;
        }
        __syncthreads();
        #pragma unroll
        for (int ks = 0; ks < 2; ++ks) {
            int chunk = ks * 4 + (lane >> 4);
            short8 af[4], bfr[4];
            #pragma unroll
            for (int i = 0; i < 4; ++i) af[i] = frag_ld(As, wm + i * 16 + (lane & 15), chunk);
            #pragma unroll
            for (int j = 0; j < 4; ++j) bfr[j] = frag_ld(Bs, wn + j * 16 + (lane & 15), chunk);
            #pragma unroll
            for (int i = 0; i < 4; ++i)
                #pragma unroll
                for (int j = 0; j < 4; ++j)
                    acc[i][j] = __builtin_amdgcn_mfma_f32_16x16x32_bf16(af[i], bfr[j], acc[i][j], 0, 0, 0);
        }
        __syncthreads();
    }
    #pragma unroll
    for (int i = 0; i < 4; ++i) {
        #pragma unroll
        for (int j = 0; j < 4; ++j) {
            int col = col0 + wn + j * 16 + (lane & 15);
            if (col >= N) continue;
            float bv = bias ? bias[col] : 0.f;
            #pragma unroll
            for (int rg = 0; rg < 4; ++rg) {
                int row = row0 + wm + i * 16 + (lane >> 4) * 4 + rg;
                if (row >= M) continue;
                float v = acc[i][j][rg] + bv;
                if (OUTBF16) ((unsigned short*)Cp)[(size_t)row * ldC + col] = f2bu(v);
                else         ((float*)Cp)[(size_t)row * ldC + col] = v;
            }
        }
    }
}

// small per-step GEMM: C[64 x N] = A[64 x K] * BT[N x K]^T (+bias or +initrow)
__global__ __launch_bounds__(256) void k_gemm64(
        const unsigned short* __restrict__ A, int sA,
        const unsigned short* __restrict__ BT, int sB,
        const float* __restrict__ bias,
        const unsigned short* __restrict__ initrow, int ldI,
        float* __restrict__ C, int ldC, int K) {
    __shared__ unsigned short As[64 * 64];
    __shared__ unsigned short Bs[64 * 64];
    int tid = threadIdx.x;
    int col0 = blockIdx.x * 64;
    int w = tid >> 6, lane = tid & 63;
    int wrow = w * 16;
    floatx4 acc[4] = {};
    for (int k0 = 0; k0 < K; k0 += 64) {
        #pragma unroll
        for (int i = 0; i < 2; ++i) {
            int e = (tid + i * 256) * 8;
            int r = e >> 6, k = e & 63;
            int sw = ((k >> 3) ^ (r & 7)) << 3;
            *(uint4*)(As + r * 64 + sw) = *(const uint4*)(A + (size_t)r * sA + k0 + k);
            *(uint4*)(Bs + r * 64 + sw) = *(const uint4*)(BT + (size_t)(col0 + r) * sB + k0 + k);
        }
        __syncthreads();
        #pragma unroll
        for (int ks = 0; ks < 2; ++ks) {
            int chunk = ks * 4 + (lane >> 4);
            short8 a = frag_ld(As, wrow + (lane & 15), chunk);
            #pragma unroll
            for (int j = 0; j < 4; ++j) {
                short8 b = frag_ld(Bs, j * 16 + (lane & 15), chunk);
                acc[j] = __builtin_amdgcn_mfma_f32_16x16x32_bf16(a, b, acc[j], 0, 0, 0);
            }
        }
        __syncthreads();
    }
    #pragma unroll
    for (int j = 0; j < 4; ++j) {
        int col = col0 + j * 16 + (lane & 15);
        float bv = bias ? bias[col] : 0.f;
        #pragma unroll
        for (int rg = 0; rg < 4; ++rg) {
            int row = wrow + (lane >> 4) * 4 + rg;
            float v = acc[j][rg] + bv;
            if (initrow) v += bu2f(initrow[(size_t)row * ldI + col]);
            C[(size_t)row * ldC + col] = v;
        }
    }
}

// ---------------- per-step fused kernels ----------------

// e = leaky(att1[b,p,:]+att2[b,:]) @ wf + bfull; softmax over p; write alpha & alphas
__global__ void k_essm(const unsigned short* __restrict__ att1, const float* __restrict__ att2,
                       const float* __restrict__ wf, const float* __restrict__ bfull,
                       float* __restrict__ alpha, float* __restrict__ out_alpha, int t) {
    __shared__ float e_s[256];
    __shared__ float red[256];
    int b = blockIdx.x, tid = threadIdx.x;
    int w = tid >> 6, lane = tid & 63;
    float a2[8], wv[8];
    #pragma unroll
    for (int i = 0; i < 8; ++i) {
        int a = lane * 8 + i;
        a2[i] = att2[b * A_ + a];
        wv[i] = wf[a];
    }
    if (tid >= P_) e_s[tid] = -1e30f;
    float bf0 = bfull[0];
    for (int p = w; p < P_; p += 4) {
        short8 s = *(const short8*)(att1 + ((size_t)(b * P_ + p)) * A_ + lane * 8);
        float acc = 0.f;
        #pragma unroll
        for (int i = 0; i < 8; ++i) {
            float x = bu2f((unsigned short)s[i]) + a2[i];
            x = x >= 0.f ? x : 0.2f * x;
            acc += x * wv[i];
        }
        acc = wave_reduce(acc);
        if (lane == 0) e_s[p] = acc + bf0;
    }
    __syncthreads();
    float v = e_s[tid];
    red[tid] = v;
    __syncthreads();
    for (int s2 = 128; s2; s2 >>= 1) {
        if (tid < s2) red[tid] = fmaxf(red[tid], red[tid + s2]);
        __syncthreads();
    }
    float m = red[0];
    __syncthreads();
    float ex = (tid < P_) ? expf(v - m) : 0.f;
    red[tid] = ex;
    __syncthreads();
    for (int s2 = 128; s2; s2 >>= 1) {
        if (tid < s2) red[tid] += red[tid + s2];
        __syncthreads();
    }
    float inv = 1.f / red[0];
    if (tid < P_) {
        float al = ex * inv;
        alpha[b * P_ + tid] = al;
        out_alpha[((size_t)b * T_ + t) * P_ + tid] = al;
    }
}

// ep[b,e] = sum_p alpha[b,p] * imgW[b,p,e]   (imgW includes W_embed bias since sum(alpha)=1)
__global__ void k_epsum(const unsigned short* __restrict__ imgW, const float* __restrict__ alpha,
                        unsigned short* __restrict__ ep) {
    __shared__ float al[P_];
    int b = blockIdx.x, tid = threadIdx.x;
    for (int i = tid; i < P_; i += 256) al[i] = alpha[b * P_ + i];
    __syncthreads();
    int e = blockIdx.y * 256 + tid;
    const unsigned short* base = imgW + (size_t)b * P_ * E_ + e;
    float s = 0.f;
    #pragma unroll 4
    for (int p = 0; p < P_; ++p) s += al[p] * bu2f(base[(size_t)p * E_]);
    ep[(size_t)b * E_ + e] = f2bu(s);
}

// GRU combine, fp32 recurrence; also write bf16 h into hseq[t]
__global__ void k_gru(const float* __restrict__ gi, const float* __restrict__ gh,
                      const float* __restrict__ h, float* __restrict__ hn,
                      unsigned short* __restrict__ hseq_t) {
    int idx = blockIdx.x * blockDim.x + threadIdx.x;
    if (idx >= B_ * H_) return;
    int b = idx >> 9, hh = idx & 511;
    const float* gib = gi + (size_t)b * 3 * H_;
    const float* ghb = gh + (size_t)b * 3 * H_;
    float r = 1.f / (1.f + expf(-(gib[hh] + ghb[hh])));
    float z = 1.f / (1.f + expf(-(gib[H_ + hh] + ghb[H_ + hh])));
    float n = tanhf(gib[2 * H_ + hh] + r * ghb[2 * H_ + hh]);
    float v = (1.f - z) * n + z * h[idx];
    hn[idx] = v;
    hseq_t[idx] = f2bu(v);
}

extern "C" void kernel_launch(void* const* d_in, const int* in_sizes, int n_in,
                              void* d_out, int out_size, void* d_ws, size_t ws_size,
                              hipStream_t stream) {
    const float* cnn   = (const float*)d_in[0];
    const int*   icap  = (const int*)d_in[1];   // harness normalizes integers to int32
    // d_in[2] caption_size unused (all == T)
    const float* emb   = (const float*)d_in[3];
    const float* Wenc  = (const float*)d_in[4];
    const float* benc  = (const float*)d_in[5];
    const float* Wdec  = (const float*)d_in[6];
    const float* bdec  = (const float*)d_in[7];
    const float* wfull = (const float*)d_in[8];
    const float* bfull = (const float*)d_in[9];
    const float* Winit = (const float*)d_in[10];
    const float* binit = (const float*)d_in[11];
    const float* Wemb  = (const float*)d_in[12];
    const float* bemb  = (const float*)d_in[13];
    const float* Wih   = (const float*)d_in[14];
    const float* bih   = (const float*)d_in[15];
    const float* Whh   = (const float*)d_in[16];
    const float* bhh   = (const float*)d_in[17];
    const float* Wout  = (const float*)d_in[18];
    const float* bout  = (const float*)d_in[19];

    float* out_pred  = (float*)d_out;
    float* out_alpha = out_pred + (size_t)T_ * B_ * V_;

    char* w = (char*)d_ws;
    auto carve = [&](size_t bytes) -> char* {
        char* p = w;
        w += (bytes + 255) & ~(size_t)255;
        return p;
    };
    unsigned short* att1  = (unsigned short*)carve((size_t)B_ * P_ * A_ * 2);  // 12.85 MB
    unsigned short* imgW  = (unsigned short*)carve((size_t)B_ * P_ * E_ * 2);  // 12.85 MB
    unsigned short* WoutT = (unsigned short*)carve((size_t)V_ * H_ * 2);       // 30.72 MB
    unsigned short* WencT = (unsigned short*)carve((size_t)A_ * F_ * 2);
    unsigned short* WembT = (unsigned short*)carve((size_t)E_ * F_ * 2);
    unsigned short* WdecT = (unsigned short*)carve((size_t)A_ * H_ * 2);
    unsigned short* Wihb  = (unsigned short*)carve((size_t)3 * H_ * 2 * E_ * 2);
    unsigned short* Whhb  = (unsigned short*)carve((size_t)3 * H_ * H_ * 2);
    unsigned short* gitok = (unsigned short*)carve((size_t)T_ * B_ * 3 * H_ * 2); // 4.9 MB
    unsigned short* ce    = (unsigned short*)carve((size_t)T_ * B_ * E_ * 2);
    unsigned short* hseq  = (unsigned short*)carve((size_t)T_ * B_ * H_ * 2);
    unsigned short* h0b   = (unsigned short*)carve((size_t)B_ * H_ * 2);
    unsigned short* ep    = (unsigned short*)carve((size_t)B_ * E_ * 2);
    float* meanf = (float*)carve((size_t)B_ * F_ * 4);
    float* hbuf0 = (float*)carve((size_t)B_ * H_ * 4);
    float* hbuf1 = (float*)carve((size_t)B_ * H_ * 4);
    float* att2  = (float*)carve((size_t)B_ * A_ * 4);
    float* alpha = (float*)carve((size_t)B_ * P_ * 4);
    float* gi    = (float*)carve((size_t)B_ * 3 * H_ * 4);
    float* gh    = (float*)carve((size_t)B_ * 3 * H_ * 4);

    // ---- one-time prep ----
    k_cvt<<<(3 * H_ * 2 * E_ / 4 + 255) / 256, 256, 0, stream>>>(Wih, Wihb, 3 * H_ * 2 * E_ / 4);
    k_cvt<<<(3 * H_ * H_ / 4 + 255) / 256, 256, 0, stream>>>(Whh, Whhb, 3 * H_ * H_ / 4);
    k_tc<<<dim3(A_ / 64, H_ / 64), 256, 0, stream>>>(Wdec, WdecT, H_, A_);
    k_tc<<<dim3(A_ / 64, F_ / 64), 256, 0, stream>>>(Wenc, WencT, F_, A_);
    k_tc<<<dim3(E_ / 64, F_ / 64), 256, 0, stream>>>(Wemb, WembT, F_, E_);
    k_tc<<<dim3((V_ + 63) / 64, H_ / 64), 256, 0, stream>>>(Wout, WoutT, H_, V_);
    k_capemb<<<T_ * B_, 256, 0, stream>>>(emb, icap, ce);
    k_mean<<<B_ * F_ / 4, 256, 0, stream>>>(cnn, meanf);
    k_h0<<<(B_ * H_ + 255) / 256, 256, 0, stream>>>(meanf, Winit, binit, hbuf0, h0b);
    // gi_tok[t*B+b][j] = cap_emb @ W_ih[:, :E]^T + b_ih (bf16)
    k_gemm_big<0, 1><<<dim3((T_ * B_ + 127) / 128, (3 * H_) / 128), 256, 0, stream>>>(
        ce, E_, Wihb, 2 * E_, bih, gitok, 3 * H_, T_ * B_, 3 * H_, E_);
    // att1 = img @ W_enc + b_enc  (bf16)
    k_gemm_big<1, 1><<<dim3(B_ * P_ / 128, A_ / 128), 256, 0, stream>>>(
        cnn, 0, WencT, F_, benc, att1, A_, B_ * P_, A_, F_);
    // imgW = img @ W_embed + b_embed (bf16; bias folds since sum(alpha)=1)
    k_gemm_big<1, 1><<<dim3(B_ * P_ / 128, E_ / 128), 256, 0, stream>>>(
        cnn, 0, WembT, F_, bemb, imgW, E_, B_ * P_, E_, F_);

    // ---- recurrence ----
    for (int t = 0; t < T_; ++t) {
        const float* hcur = (t & 1) ? hbuf1 : hbuf0;
        float* hnext = (t & 1) ? hbuf0 : hbuf1;
        const unsigned short* hb = (t == 0) ? h0b : hseq + (size_t)(t - 1) * B_ * H_;

        k_gemm64<<<A_ / 64, 256, 0, stream>>>(hb, H_, WdecT, H_, bdec,
                                              nullptr, 0, att2, A_, H_);
        k_gemm64<<<(3 * H_) / 64, 256, 0, stream>>>(hb, H_, Whhb, H_, bhh,
                                                    nullptr, 0, gh, 3 * H_, H_);
        k_essm<<<B_, 256, 0, stream>>>(att1, att2, wfull, bfull, alpha, out_alpha, t);
        k_epsum<<<dim3(B_, 2), 256, 0, stream>>>(imgW, alpha, ep);
        k_gemm64<<<(3 * H_) / 64, 256, 0, stream>>>(ep, E_, Wihb + E_, 2 * E_, nullptr,
                                                    gitok + (size_t)t * B_ * 3 * H_, 3 * H_,
                                                    gi, 3 * H_, E_);
        k_gru<<<(B_ * H_ + 255) / 256, 256, 0, stream>>>(gi, gh, hcur, hnext,
                                                         hseq + (size_t)t * B_ * H_);
    }

    // ---- hoisted output projection: [T*B,512] x [512,30000] ----
    k_gemm_big<0, 0><<<dim3((T_ * B_ + 127) / 128, (V_ + 127) / 128), 256, 0, stream>>>(
        hseq, H_, WoutT, H_, bout, out_pred, V_, T_ * B_, V_, H_);
}

// Round 2
// 2623.393 us; speedup vs baseline: 3.2928x; 1.3810x over previous
//
#include <hip/hip_runtime.h>

#define B_   64
#define F_   2048
#define P_   196
#define T_   25
#define E_   512
#define H_   512
#define A_   512
#define V_   30000

typedef __attribute__((ext_vector_type(8))) short short8;
typedef __attribute__((ext_vector_type(4))) float floatx4;

__device__ __forceinline__ float bu2f(unsigned short u) {
    union { unsigned int i; float f; } c; c.i = ((unsigned int)u) << 16; return c.f;
}
__device__ __forceinline__ unsigned short f2bu(float x) {
    unsigned int u = __float_as_uint(x);
    return (unsigned short)((u + 0x7FFFu + ((u >> 16) & 1u)) >> 16);  // RNE
}
__device__ __forceinline__ float wave_reduce(float v) {
    #pragma unroll
    for (int off = 32; off; off >>= 1) v += __shfl_down(v, off);
    return v;
}

// ---------------- one-time prep ----------------

// mean over P: meanf[b*F+f]
__global__ void k_mean(const float* __restrict__ cnn, float* __restrict__ meanf) {
    int wave = (blockIdx.x * blockDim.x + threadIdx.x) >> 6;
    int lane = threadIdx.x & 63;
    if (wave >= B_ * F_) return;
    const float* row = cnn + (size_t)wave * P_;
    float acc = 0.f;
    for (int p = lane; p < P_; p += 64) acc += row[p];
    acc = wave_reduce(acc);
    if (lane == 0) meanf[wave] = acc * (1.0f / P_);
}

// h0 = meanf @ W_init + b_init (fp32 exact) + bf16 copy
__global__ void k_h0(const float* __restrict__ meanf, const float* __restrict__ Wi,
                     const float* __restrict__ bi, float* __restrict__ h0,
                     unsigned short* __restrict__ h0b) {
    int idx = blockIdx.x * blockDim.x + threadIdx.x;
    if (idx >= B_ * H_) return;
    int b = idx >> 9, h = idx & 511;
    const float* m = meanf + (size_t)b * F_;
    const float* w = Wi + h;
    float a0 = 0.f, a1 = 0.f, a2 = 0.f, a3 = 0.f;
    for (int f = 0; f < F_; f += 4) {
        a0 += m[f + 0] * w[(size_t)(f + 0) * H_];
        a1 += m[f + 1] * w[(size_t)(f + 1) * H_];
        a2 += m[f + 2] * w[(size_t)(f + 2) * H_];
        a3 += m[f + 3] * w[(size_t)(f + 3) * H_];
    }
    float v = a0 + a1 + a2 + a3 + bi[h];
    h0[idx] = v;
    h0b[idx] = f2bu(v);
}

// fp32 -> bf16 convert
__global__ void k_cvt(const float* __restrict__ in, unsigned short* __restrict__ out, int n4) {
    int i = blockIdx.x * blockDim.x + threadIdx.x;
    if (i >= n4) return;
    float4 v = ((const float4*)in)[i];
    ushort4 o;
    o.x = f2bu(v.x); o.y = f2bu(v.y); o.z = f2bu(v.z); o.w = f2bu(v.w);
    ((ushort4*)out)[i] = o;
}

// transpose-convert: in fp32 [R][C] -> out bf16 [C][R]
__global__ void k_tc(const float* __restrict__ in, unsigned short* __restrict__ out,
                     int R, int C) {
    __shared__ float tile[64][65];
    int tid = threadIdx.x;
    int c0 = blockIdx.x * 64, r0 = blockIdx.y * 64;
    #pragma unroll
    for (int i = 0; i < 16; ++i) {
        int r = (tid >> 6) + i * 4, c = tid & 63;
        tile[r][c] = (r0 + r < R && c0 + c < C) ? in[(size_t)(r0 + r) * C + c0 + c] : 0.f;
    }
    __syncthreads();
    #pragma unroll
    for (int i = 0; i < 16; ++i) {
        int c = (tid >> 6) + i * 4, r = tid & 63;
        if (c0 + c < C && r0 + r < R)
            out[(size_t)(c0 + c) * R + r0 + r] = f2bu(tile[r][c]);
    }
}

// cnn [64][2048][196] fp32 -> cnnT [b*196+p][2048] bf16
__global__ void k_tcnn(const float* __restrict__ cnn, unsigned short* __restrict__ cnnT) {
    __shared__ float tile[64][65];
    int b = blockIdx.z;
    int f0 = blockIdx.x * 64, p0 = blockIdx.y * 64;
    int tid = threadIdx.x;
    int c = tid & 63, rr = tid >> 6;
    #pragma unroll
    for (int i = 0; i < 16; ++i) {
        int r = rr + i * 4;
        int p = p0 + c;
        tile[r][c] = (p < P_) ? cnn[((size_t)b * F_ + f0 + r) * P_ + p] : 0.f;
    }
    __syncthreads();
    #pragma unroll
    for (int i = 0; i < 16; ++i) {
        int pr = rr + i * 4;
        int p = p0 + pr;
        if (p < P_)
            cnnT[((size_t)b * P_ + p) * F_ + f0 + c] = f2bu(tile[c][pr]);
    }
}

// biasc = [benc ; bemb]  (1024)
__global__ void k_bias2(const float* __restrict__ a, const float* __restrict__ b,
                        float* __restrict__ o) {
    int i = blockIdx.x * blockDim.x + threadIdx.x;
    if (i < 512) o[i] = a[i];
    else if (i < 1024) o[i] = b[i - 512];
}

// gather caption embeddings -> bf16 [T*B][E], row = t*64+b
__global__ void k_capemb(const float* __restrict__ emb, const int* __restrict__ icap,
                         unsigned short* __restrict__ ce) {
    int row = blockIdx.x;
    int t = row >> 6, b = row & 63;
    int tok = icap[b * T_ + t];
    const float* src = emb + (size_t)tok * E_;
    unsigned short* dst = ce + (size_t)row * E_;
    int e = threadIdx.x;
    dst[e] = f2bu(src[e]);
    dst[e + 256] = f2bu(src[e + 256]);
}

// ---------------- MFMA GEMMs ----------------
// LDS tile layout: [rows][64 k] bf16, 8-bf16 chunk XOR-swizzled by (row&7)
__device__ __forceinline__ short8 frag_ld(const unsigned short* T, int row, int chunk) {
    return *(const short8*)(T + row * 64 + (((chunk) ^ (row & 7)) << 3));
}

// C[M x N] = A[M x K] * BT[N x K]^T (+bias), A bf16 row-major stride sA
template<int OUTBF16>
__global__ __launch_bounds__(256) void k_gemm_big(
        const unsigned short* __restrict__ A, int sA,
        const unsigned short* __restrict__ BT, int sB,
        const float* __restrict__ bias,
        void* __restrict__ Cp, int ldC, int M, int N, int K) {
    __shared__ unsigned short As[128 * 64];
    __shared__ unsigned short Bs[128 * 64];
    int tid = threadIdx.x;
    int row0 = blockIdx.x * 128, col0 = blockIdx.y * 128;
    int w = tid >> 6, lane = tid & 63;
    int wm = (w >> 1) * 64, wn = (w & 1) * 64;
    floatx4 acc[4][4] = {};
    for (int k0 = 0; k0 < K; k0 += 64) {
        #pragma unroll
        for (int i = 0; i < 4; ++i) {
            int e = (tid + i * 256) * 8;
            int r = e >> 6, k = e & 63;
            uint4 v = make_uint4(0, 0, 0, 0);
            int gr = row0 + r;
            if (gr < M) v = *(const uint4*)(A + (size_t)gr * sA + k0 + k);
            *(uint4*)(As + r * 64 + (((k >> 3) ^ (r & 7)) << 3)) = v;
        }
        #pragma unroll
        for (int i = 0; i < 4; ++i) {
            int e = (tid + i * 256) * 8;
            int r = e >> 6, k = e & 63;
            uint4 v = make_uint4(0, 0, 0, 0);
            int gc = col0 + r;
            if (gc < N) v = *(const uint4*)(BT + (size_t)gc * sB + k0 + k);
            *(uint4*)(Bs + r * 64 + (((k >> 3) ^ (r & 7)) << 3)) = v;
        }
        __syncthreads();
        #pragma unroll
        for (int ks = 0; ks < 2; ++ks) {
            int chunk = ks * 4 + (lane >> 4);
            short8 af[4], bfr[4];
            #pragma unroll
            for (int i = 0; i < 4; ++i) af[i] = frag_ld(As, wm + i * 16 + (lane & 15), chunk);
            #pragma unroll
            for (int j = 0; j < 4; ++j) bfr[j] = frag_ld(Bs, wn + j * 16 + (lane & 15), chunk);
            #pragma unroll
            for (int i = 0; i < 4; ++i)
                #pragma unroll
                for (int j = 0; j < 4; ++j)
                    acc[i][j] = __builtin_amdgcn_mfma_f32_16x16x32_bf16(af[i], bfr[j], acc[i][j], 0, 0, 0);
        }
        __syncthreads();
    }
    #pragma unroll
    for (int i = 0; i < 4; ++i) {
        #pragma unroll
        for (int j = 0; j < 4; ++j) {
            int col = col0 + wn + j * 16 + (lane & 15);
            if (col >= N) continue;
            float bv = bias ? bias[col] : 0.f;
            #pragma unroll
            for (int rg = 0; rg < 4; ++rg) {
                int row = row0 + wm + i * 16 + (lane >> 4) * 4 + rg;
                if (row >= M) continue;
                float v = acc[i][j][rg] + bv;
                if (OUTBF16) ((unsigned short*)Cp)[(size_t)row * ldC + col] = f2bu(v);
                else         ((float*)Cp)[(size_t)row * ldC + col] = v;
            }
        }
    }
}

// ---------------- per-step kernels ----------------

// gi/gh GEMM, one launch. blocks 0..23: gi = ep@Wih[:,E:]^T + gitok[t]
//                         blocks 24..47: gh = hb@Whh^T + bhh
// K=512 fixed, LDS double-buffered, reg prefetch, 1 barrier/K-step.
__global__ __launch_bounds__(256) void k_gates(
        const unsigned short* __restrict__ ep, const unsigned short* __restrict__ hb,
        const unsigned short* __restrict__ Wihb, const unsigned short* __restrict__ Whhb,
        const float* __restrict__ bhh, const unsigned short* __restrict__ gitok_t,
        float* __restrict__ gi, float* __restrict__ gh) {
    __shared__ unsigned short As[2][64 * 64];
    __shared__ unsigned short Bs[2][64 * 64];
    int tid = threadIdx.x;
    int gid = blockIdx.x;
    bool is_gi = gid < 24;
    int col0 = (is_gi ? gid : gid - 24) * 64;
    const unsigned short* A  = is_gi ? ep : hb;           // [64][512]
    const unsigned short* BT = is_gi ? (Wihb + E_) : Whhb;
    int sB = is_gi ? (2 * E_) : H_;
    float* C = is_gi ? gi : gh;

    int w = tid >> 6, lane = tid & 63;
    int wrow = w * 16;
    floatx4 acc[4] = {};

    int e0 = tid * 8,        r0 = e0 >> 6, kk0 = e0 & 63;
    int e1 = (tid + 256) * 8, r1 = e1 >> 6, kk1 = e1 & 63;
    int sw0 = r0 * 64 + (((kk0 >> 3) ^ (r0 & 7)) << 3);
    int sw1 = r1 * 64 + (((kk1 >> 3) ^ (r1 & 7)) << 3);

    *(uint4*)(As[0] + sw0) = *(const uint4*)(A + (size_t)r0 * 512 + kk0);
    *(uint4*)(As[0] + sw1) = *(const uint4*)(A + (size_t)r1 * 512 + kk1);
    *(uint4*)(Bs[0] + sw0) = *(const uint4*)(BT + (size_t)(col0 + r0) * sB + kk0);
    *(uint4*)(Bs[0] + sw1) = *(const uint4*)(BT + (size_t)(col0 + r1) * sB + kk1);
    __syncthreads();

    #pragma unroll
    for (int ks = 0; ks < 8; ++ks) {
        int cb = ks & 1, nb = cb ^ 1;
        uint4 ra0, ra1, rb0, rb1;
        if (ks < 7) {
            int k0 = (ks + 1) * 64;
            ra0 = *(const uint4*)(A + (size_t)r0 * 512 + k0 + kk0);
            ra1 = *(const uint4*)(A + (size_t)r1 * 512 + k0 + kk1);
            rb0 = *(const uint4*)(BT + (size_t)(col0 + r0) * sB + k0 + kk0);
            rb1 = *(const uint4*)(BT + (size_t)(col0 + r1) * sB + k0 + kk1);
        }
        #pragma unroll
        for (int kc = 0; kc < 2; ++kc) {
            int chunk = kc * 4 + (lane >> 4);
            short8 a = frag_ld(As[cb], wrow + (lane & 15), chunk);
            #pragma unroll
            for (int j = 0; j < 4; ++j) {
                short8 b = frag_ld(Bs[cb], j * 16 + (lane & 15), chunk);
                acc[j] = __builtin_amdgcn_mfma_f32_16x16x32_bf16(a, b, acc[j], 0, 0, 0);
            }
        }
        if (ks < 7) {
            *(uint4*)(As[nb] + sw0) = ra0;
            *(uint4*)(As[nb] + sw1) = ra1;
            *(uint4*)(Bs[nb] + sw0) = rb0;
            *(uint4*)(Bs[nb] + sw1) = rb1;
            __syncthreads();
        }
    }
    #pragma unroll
    for (int j = 0; j < 4; ++j) {
        int col = col0 + j * 16 + (lane & 15);
        #pragma unroll
        for (int rg = 0; rg < 4; ++rg) {
            int row = wrow + (lane >> 4) * 4 + rg;
            float v = acc[j][rg];
            if (is_gi) v += bu2f(gitok_t[(size_t)row * (3 * H_) + col]);
            else       v += bhh[col];
            C[(size_t)row * (3 * H_) + col] = v;
        }
    }
}

// Per batch-row block: att2 = hb@Wdec + bdec (VALU), e = leaky(att1+att2)@wf + bfull,
// softmax -> alpha (+out_alpha), ep = sum_p alpha * imgW   (attc: cols 0-511 att1, 512-1023 imgW)
__global__ __launch_bounds__(256) void k_essm_ep(
        const unsigned short* __restrict__ attc, const unsigned short* __restrict__ hb,
        const unsigned short* __restrict__ WdecT, const float* __restrict__ bdec,
        const float* __restrict__ wf, const float* __restrict__ bfull,
        float* __restrict__ out_alpha, unsigned short* __restrict__ ep, int t) {
    __shared__ float hs[512];
    __shared__ float a2s[512];
    __shared__ float e_s[256];
    __shared__ float red[256];
    __shared__ float al[P_];
    int b = blockIdx.x, tid = threadIdx.x;
    int w = tid >> 6, lane = tid & 63;
    size_t rowb = (size_t)b * P_;

    hs[tid] = bu2f(hb[(size_t)b * H_ + tid]);
    hs[tid + 256] = bu2f(hb[(size_t)b * H_ + tid + 256]);
    if (tid >= P_) e_s[tid] = -1e30f;
    __syncthreads();

    // att2 for a = tid and tid+256
    {
        float acc0 = 0.f, acc1 = 0.f;
        const unsigned short* w0 = WdecT + (size_t)tid * 512;
        const unsigned short* w1 = WdecT + (size_t)(tid + 256) * 512;
        for (int kk = 0; kk < 512; kk += 8) {
            short8 x0 = *(const short8*)(w0 + kk);
            short8 x1 = *(const short8*)(w1 + kk);
            #pragma unroll
            for (int i = 0; i < 8; ++i) {
                float hv = hs[kk + i];
                acc0 += bu2f((unsigned short)x0[i]) * hv;
                acc1 += bu2f((unsigned short)x1[i]) * hv;
            }
        }
        a2s[tid] = acc0 + bdec[tid];
        a2s[tid + 256] = acc1 + bdec[tid + 256];
    }
    __syncthreads();

    // e-scores: wave w handles p = w, w+4, ...
    float a2v[8], wv[8];
    #pragma unroll
    for (int i = 0; i < 8; ++i) {
        a2v[i] = a2s[lane * 8 + i];
        wv[i] = wf[lane * 8 + i];
    }
    float bf0 = bfull[0];
    for (int p = w; p < P_; p += 4) {
        short8 s = *(const short8*)(attc + (rowb + p) * 1024 + lane * 8);
        float acc = 0.f;
        #pragma unroll
        for (int i = 0; i < 8; ++i) {
            float x = bu2f((unsigned short)s[i]) + a2v[i];
            x = x >= 0.f ? x : 0.2f * x;
            acc += x * wv[i];
        }
        acc = wave_reduce(acc);
        if (lane == 0) e_s[p] = acc + bf0;
    }
    __syncthreads();

    // softmax over 196
    float v = e_s[tid];
    red[tid] = v;
    __syncthreads();
    for (int s2 = 128; s2; s2 >>= 1) {
        if (tid < s2) red[tid] = fmaxf(red[tid], red[tid + s2]);
        __syncthreads();
    }
    float m = red[0];
    __syncthreads();
    float ex = (tid < P_) ? expf(v - m) : 0.f;
    red[tid] = ex;
    __syncthreads();
    for (int s2 = 128; s2; s2 >>= 1) {
        if (tid < s2) red[tid] += red[tid + s2];
        __syncthreads();
    }
    float inv = 1.f / red[0];
    if (tid < P_) {
        float a = ex * inv;
        al[tid] = a;
        out_alpha[((size_t)b * T_ + t) * P_ + tid] = a;
    }
    __syncthreads();

    // ep[e] = sum_p al[p] * imgW[p][e]
    {
        float s0 = 0.f, s1 = 0.f;
        const unsigned short* base = attc + rowb * 1024 + 512;
        for (int p = 0; p < P_; ++p) {
            float av = al[p];
            s0 += av * bu2f(base[(size_t)p * 1024 + tid]);
            s1 += av * bu2f(base[(size_t)p * 1024 + tid + 256]);
        }
        ep[(size_t)b * E_ + tid] = f2bu(s0);
        ep[(size_t)b * E_ + tid + 256] = f2bu(s1);
    }
}

// GRU combine, fp32 recurrence; also write bf16 h into hseq[t]
__global__ void k_gru(const float* __restrict__ gi, const float* __restrict__ gh,
                      const float* __restrict__ h, float* __restrict__ hn,
                      unsigned short* __restrict__ hseq_t) {
    int idx = blockIdx.x * blockDim.x + threadIdx.x;
    if (idx >= B_ * H_) return;
    int b = idx >> 9, hh = idx & 511;
    const float* gib = gi + (size_t)b * 3 * H_;
    const float* ghb = gh + (size_t)b * 3 * H_;
    float r = 1.f / (1.f + expf(-(gib[hh] + ghb[hh])));
    float z = 1.f / (1.f + expf(-(gib[H_ + hh] + ghb[H_ + hh])));
    float n = tanhf(gib[2 * H_ + hh] + r * ghb[2 * H_ + hh]);
    float v = (1.f - z) * n + z * h[idx];
    hn[idx] = v;
    hseq_t[idx] = f2bu(v);
}

extern "C" void kernel_launch(void* const* d_in, const int* in_sizes, int n_in,
                              void* d_out, int out_size, void* d_ws, size_t ws_size,
                              hipStream_t stream) {
    const float* cnn   = (const float*)d_in[0];
    const int*   icap  = (const int*)d_in[1];
    // d_in[2] caption_size unused (all == T)
    const float* emb   = (const float*)d_in[3];
    const float* Wenc  = (const float*)d_in[4];
    const float* benc  = (const float*)d_in[5];
    const float* Wdec  = (const float*)d_in[6];
    const float* bdec  = (const float*)d_in[7];
    const float* wfull = (const float*)d_in[8];
    const float* bfull = (const float*)d_in[9];
    const float* Winit = (const float*)d_in[10];
    const float* binit = (const float*)d_in[11];
    const float* Wemb  = (const float*)d_in[12];
    const float* bemb  = (const float*)d_in[13];
    const float* Wih   = (const float*)d_in[14];
    const float* bih   = (const float*)d_in[15];
    const float* Whh   = (const float*)d_in[16];
    const float* bhh   = (const float*)d_in[17];
    const float* Wout  = (const float*)d_in[18];
    const float* bout  = (const float*)d_in[19];

    float* out_pred  = (float*)d_out;
    float* out_alpha = out_pred + (size_t)T_ * B_ * V_;

    char* w = (char*)d_ws;
    auto carve = [&](size_t bytes) -> char* {
        char* p = w;
        w += (bytes + 255) & ~(size_t)255;
        return p;
    };
    // cnnT (51.4 MB) dead after the fused GEMM; WoutT (30.7 MB) built after it -> alias
    char* reuse = carve((size_t)B_ * P_ * F_ * 2);
    unsigned short* cnnT  = (unsigned short*)reuse;
    unsigned short* WoutT = (unsigned short*)reuse;
    unsigned short* attc  = (unsigned short*)carve((size_t)B_ * P_ * 1024 * 2); // att1|imgW, 25.7 MB
    unsigned short* WencT = (unsigned short*)carve((size_t)A_ * F_ * 2);        // adjacent to
    unsigned short* WembT = (unsigned short*)carve((size_t)E_ * F_ * 2);        // ... WembT (N=1024)
    unsigned short* WdecT = (unsigned short*)carve((size_t)A_ * H_ * 2);
    unsigned short* Wihb  = (unsigned short*)carve((size_t)3 * H_ * 2 * E_ * 2);
    unsigned short* Whhb  = (unsigned short*)carve((size_t)3 * H_ * H_ * 2);
    unsigned short* gitok = (unsigned short*)carve((size_t)T_ * B_ * 3 * H_ * 2);
    unsigned short* ce    = (unsigned short*)carve((size_t)T_ * B_ * E_ * 2);
    unsigned short* hseq  = (unsigned short*)carve((size_t)T_ * B_ * H_ * 2);
    unsigned short* h0b   = (unsigned short*)carve((size_t)B_ * H_ * 2);
    unsigned short* ep    = (unsigned short*)carve((size_t)B_ * E_ * 2);
    float* biasc = (float*)carve(1024 * 4);
    float* meanf = (float*)carve((size_t)B_ * F_ * 4);
    float* hbuf0 = (float*)carve((size_t)B_ * H_ * 4);
    float* hbuf1 = (float*)carve((size_t)B_ * H_ * 4);
    float* gi    = (float*)carve((size_t)B_ * 3 * H_ * 4);
    float* gh    = (float*)carve((size_t)B_ * 3 * H_ * 4);

    // ---- one-time prep ----
    k_tcnn<<<dim3(F_ / 64, 4, B_), 256, 0, stream>>>(cnn, cnnT);
    k_cvt<<<(3 * H_ * 2 * E_ / 4 + 255) / 256, 256, 0, stream>>>(Wih, Wihb, 3 * H_ * 2 * E_ / 4);
    k_cvt<<<(3 * H_ * H_ / 4 + 255) / 256, 256, 0, stream>>>(Whh, Whhb, 3 * H_ * H_ / 4);
    k_tc<<<dim3(A_ / 64, H_ / 64), 256, 0, stream>>>(Wdec, WdecT, H_, A_);
    k_tc<<<dim3(A_ / 64, F_ / 64), 256, 0, stream>>>(Wenc, WencT, F_, A_);
    k_tc<<<dim3(E_ / 64, F_ / 64), 256, 0, stream>>>(Wemb, WembT, F_, E_);
    k_bias2<<<4, 256, 0, stream>>>(benc, bemb, biasc);
    k_capemb<<<T_ * B_, 256, 0, stream>>>(emb, icap, ce);
    k_mean<<<B_ * F_ / 4, 256, 0, stream>>>(cnn, meanf);
    k_h0<<<(B_ * H_ + 255) / 256, 256, 0, stream>>>(meanf, Winit, binit, hbuf0, h0b);
    // gi_tok[t*B+b][j] = cap_emb @ W_ih[:, :E]^T + b_ih (bf16)
    k_gemm_big<1><<<dim3((T_ * B_ + 127) / 128, (3 * H_) / 128), 256, 0, stream>>>(
        ce, E_, Wihb, 2 * E_, bih, gitok, 3 * H_, T_ * B_, 3 * H_, E_);
    // attc = img @ [W_enc | W_embed] + [b_enc | b_emb]  (N=1024, one pass over cnnT)
    k_gemm_big<1><<<dim3(B_ * P_ / 128, 1024 / 128), 256, 0, stream>>>(
        cnnT, F_, WencT, F_, biasc, attc, 1024, B_ * P_, 1024, F_);
    // WoutT over cnnT's memory (cnnT dead now)
    k_tc<<<dim3((V_ + 63) / 64, H_ / 64), 256, 0, stream>>>(Wout, WoutT, H_, V_);

    // ---- recurrence: 3 kernels/step ----
    for (int t = 0; t < T_; ++t) {
        const float* hcur = (t & 1) ? hbuf1 : hbuf0;
        float* hnext = (t & 1) ? hbuf0 : hbuf1;
        const unsigned short* hb = (t == 0) ? h0b : hseq + (size_t)(t - 1) * B_ * H_;

        k_essm_ep<<<B_, 256, 0, stream>>>(attc, hb, WdecT, bdec, wfull, bfull,
                                          out_alpha, ep, t);
        k_gates<<<48, 256, 0, stream>>>(ep, hb, Wihb, Whhb, bhh,
                                        gitok + (size_t)t * B_ * 3 * H_, gi, gh);
        k_gru<<<(B_ * H_ + 255) / 256, 256, 0, stream>>>(gi, gh, hcur, hnext,
                                                         hseq + (size_t)t * B_ * H_);
    }

    // ---- hoisted output projection: [T*B,512] x [512,30000] ----
    k_gemm_big<0><<<dim3((T_ * B_ + 127) / 128, (V_ + 127) / 128), 256, 0, stream>>>(
        hseq, H_, WoutT, H_, bout, out_pred, V_, T_ * B_, V_, H_);
}